// Round 7
// baseline (117.450 us; speedup 1.0000x reference)
//
#include <hip/hip_runtime.h>
#include <hip/hip_bf16.h>

#define B_ 16
#define T_ 2048
#define C_ 1024
#define HD_ 64

typedef __attribute__((ext_vector_type(8))) short bf16x8;
typedef __attribute__((ext_vector_type(4))) float f32x4;

__device__ __forceinline__ unsigned short f2bf(float f) {
  return __builtin_bit_cast(unsigned short, __float2bfloat16(f));
}

__device__ __forceinline__ bf16x8 cvt8(float4 a, float4 b) {
  bf16x8 r;
  r[0] = (short)f2bf(a.x); r[1] = (short)f2bf(a.y);
  r[2] = (short)f2bf(a.z); r[3] = (short)f2bf(a.w);
  r[4] = (short)f2bf(b.x); r[5] = (short)f2bf(b.y);
  r[6] = (short)f2bf(b.z); r[7] = (short)f2bf(b.w);
  return r;
}

// ---- W convert to per-K-step packed B-fragments ----
// wf[o], o = (kk*12 + ch*6 + f)*512 + lane*8 + e;  kk=0..31 (BK=32), ch=0..1, f=0..5.
// c16 = ch*6+f: m = c16>>2, d = (c16&3)*16 + (lane&15), k = kk*32 + (lane>>4)*8 + e.
// value = W_m[k][d]; scale 1/sqrt(C)*log2(e) folded into Wk (scores in exp2 domain).
__global__ void wconv_kernel(const float* __restrict__ Wk, const float* __restrict__ Wq,
                             const float* __restrict__ Wv, unsigned short* __restrict__ wf) {
  int o = blockIdx.x * 256 + threadIdx.x;   // 196608 total
  if (o >= 196608) return;
  int e = o & 7;
  int lane = (o >> 3) & 63;
  int t = o >> 9;              // kk*12 + ch*6 + f
  int f = t % 6;
  int ch = (t / 6) & 1;
  int kk = t / 12;
  int c16 = ch * 6 + f;
  int m = c16 >> 2;
  int d = (c16 & 3) * 16 + (lane & 15);
  int k = kk * 32 + (lane >> 4) * 8 + e;
  const float* W = (m == 0) ? Wk : (m == 1) ? Wq : Wv;
  float v = W[k * HD_ + d];
  if (m == 0) v *= 0.03125f * 1.44269504088896f;
  wf[o] = f2bf(v);
}

// ---------------- QKV projection v6: barrier-free, TLP-first ----------------
// 1024 blocks x 256 threads (4 INDEPENDENT waves; no LDS, no barriers).
// Wave (rh,ch): 16 rows x 96 cols. W global->reg: 6 contiguous 1KB wave-loads per
// K-step (L1-broadcast across paired waves; wf is L2-resident everywhere).
// Ping-pong depth-2 register prefetch (static indices), rolled loop (x2 body).
// 0 LDS + VGPR<=128 => 4 blocks/CU = 16 independent waves/CU.
__global__ __launch_bounds__(256, 4) void qkv_kernel(const float* __restrict__ x,
                                                     const unsigned short* __restrict__ wf,
                                                     unsigned short* __restrict__ kb,
                                                     unsigned short* __restrict__ qb,
                                                     unsigned short* __restrict__ vb) {
  const int tid = threadIdx.x;
  const int lane = tid & 63;
  const int w = tid >> 6;
  const int rh = w >> 1, ch = w & 1;
  const int l15 = lane & 15, lh = lane >> 4;
  const int r0 = blockIdx.x * 32 + rh * 16;

  const float* xpA = x + (size_t)(r0 + l15) * C_ + lh * 8;            // kk=0
  const float* xpB = xpA + 32;                                        // kk=1
  const unsigned short* wpA = wf + ch * 3072 + lane * 8;              // kk=0
  const unsigned short* wpB = wpA + 6144;                             // kk=1

  f32x4 acc[6];
#pragma unroll
  for (int i = 0; i < 6; ++i) acc[i] = {0.f, 0.f, 0.f, 0.f};

  bf16x8 wgA[6], wgB[6];
  float4 xA0, xA1, xB0, xB1;

#define WLOADA() do { _Pragma("unroll") for (int f_ = 0; f_ < 6; ++f_) \
    wgA[f_] = *(const bf16x8*)(wpA + f_ * 512); } while (0)
#define WLOADB() do { _Pragma("unroll") for (int f_ = 0; f_ < 6; ++f_) \
    wgB[f_] = *(const bf16x8*)(wpB + f_ * 512); } while (0)
#define XLA() do { xA0 = *(const float4*)xpA; xA1 = *(const float4*)(xpA + 4); } while (0)
#define XLB() do { xB0 = *(const float4*)xpB; xB1 = *(const float4*)(xpB + 4); } while (0)
#define COMP(WG, X0, X1)                                                          \
  do {                                                                            \
    bf16x8 a_ = cvt8(X0, X1);                                                     \
    _Pragma("unroll")                                                             \
    for (int f_ = 0; f_ < 6; ++f_)                                                \
      acc[f_] = __builtin_amdgcn_mfma_f32_16x16x32_bf16(a_, WG[f_], acc[f_], 0, 0, 0); \
  } while (0)

  // prologue: kk=0,1 in flight
  WLOADA(); XLA();
  WLOADB(); XLB();

#pragma unroll 1
  for (int it = 0; it < 16; ++it) {
    // even kk = 2*it
    COMP(wgA, xA0, xA1);
    wpA += 12288; xpA += 64;
    if (it < 15) { WLOADA(); XLA(); }           // prefetch kk+2
    // odd kk = 2*it+1
    COMP(wgB, xB0, xB1);
    wpB += 12288; xpB += 64;
    if (it < 15) { WLOADB(); XLB(); }           // prefetch kk+3
  }

#undef COMP
#undef XLB
#undef XLA
#undef WLOADB
#undef WLOADA

  // epilogue: C/D layout col=lane&15, row=(lane>>4)*4+rr (scales pre-folded in wconv)
#pragma unroll
  for (int rr = 0; rr < 4; ++rr) {
    size_t row = (size_t)(r0 + lh * 4 + rr);
    if (ch == 0) {
#pragma unroll
      for (int f = 0; f < 4; ++f)
        kb[row * HD_ + f * 16 + l15] = f2bf(acc[f][rr]);
      qb[row * HD_ + 0 + l15]  = f2bf(acc[4][rr]);
      qb[row * HD_ + 16 + l15] = f2bf(acc[5][rr]);
    } else {
      qb[row * HD_ + 32 + l15] = f2bf(acc[0][rr]);
      qb[row * HD_ + 48 + l15] = f2bf(acc[1][rr]);
#pragma unroll
      for (int f = 2; f < 6; ++f)
        vb[row * HD_ + (f - 2) * 16 + l15] = f2bf(acc[f][rr]);
    }
  }
}

// ---------------- flash attention v2 (unchanged from round 4) ----------------
__global__ __launch_bounds__(256) void attn_kernel(const unsigned short* __restrict__ kb,
                                                   const unsigned short* __restrict__ qb,
                                                   const unsigned short* __restrict__ vb,
                                                   float* __restrict__ out) {
  __shared__ __align__(16) unsigned short q_lds[2][64 * 72];
  __shared__ __align__(16) unsigned short v_lds[2][64 * 72];
  __shared__ __align__(16) unsigned short p_lds[64 * 72];

  const int tid = threadIdx.x;
  const int lane = tid & 63;
  const int w = tid >> 6;
  const int bid = blockIdx.x;
  const int idx = bid >> 4;
  const int jt = (idx < 16) ? (31 - idx) : (idx - 16);
  const int b = bid & 15;
  const int t0 = jt * 64;
  const int l15 = lane & 15;
  const int lh = lane >> 4;
  const size_t base = (size_t)b * T_ * HD_;

  const int qrow = tid >> 3, qc8 = tid & 7;
  const int vss = tid & 63, vd0 = (tid >> 6) * 8;

  bf16x8 kf[2];
#pragma unroll
  for (int ks = 0; ks < 2; ++ks)
    kf[ks] = *reinterpret_cast<const bf16x8*>(
        &kb[base + (size_t)(t0 + w * 16 + l15) * HD_ + ks * 32 + lh * 8]);

  bf16x8 qr0, qr1, vr0, vr1;
  qr0 = *reinterpret_cast<const bf16x8*>(&qb[base + (size_t)qrow * HD_ + qc8 * 8]);
  qr1 = *reinterpret_cast<const bf16x8*>(&qb[base + (size_t)(qrow + 32) * HD_ + qc8 * 8]);
  vr0 = *reinterpret_cast<const bf16x8*>(&vb[base + (size_t)vss * HD_ + vd0]);
  vr1 = *reinterpret_cast<const bf16x8*>(&vb[base + (size_t)vss * HD_ + vd0 + 32]);

  f32x4 o[4];
#pragma unroll
  for (int i = 0; i < 4; ++i) o[i] = {0.f, 0.f, 0.f, 0.f};
  float mrun[4], lrun[4];
#pragma unroll
  for (int r = 0; r < 4; ++r) { mrun[r] = -1e30f; lrun[r] = 0.f; }

  for (int j = 0; j <= jt; ++j) {
    const int buf = j & 1;
    *reinterpret_cast<bf16x8*>(&q_lds[buf][qrow * 72 + qc8 * 8]) = qr0;
    *reinterpret_cast<bf16x8*>(&q_lds[buf][(qrow + 32) * 72 + qc8 * 8]) = qr1;
#pragma unroll
    for (int jj = 0; jj < 8; ++jj) v_lds[buf][(vd0 + jj) * 72 + vss] = (unsigned short)vr0[jj];
#pragma unroll
    for (int jj = 0; jj < 8; ++jj) v_lds[buf][(vd0 + 32 + jj) * 72 + vss] = (unsigned short)vr1[jj];
    __syncthreads();

    if (j < jt) {
      const size_t sb = base + (size_t)(j + 1) * 64 * HD_;
      qr0 = *reinterpret_cast<const bf16x8*>(&qb[sb + (size_t)qrow * HD_ + qc8 * 8]);
      qr1 = *reinterpret_cast<const bf16x8*>(&qb[sb + (size_t)(qrow + 32) * HD_ + qc8 * 8]);
      vr0 = *reinterpret_cast<const bf16x8*>(&vb[sb + (size_t)vss * HD_ + vd0]);
      vr1 = *reinterpret_cast<const bf16x8*>(&vb[sb + (size_t)vss * HD_ + vd0 + 32]);
    }
    __builtin_amdgcn_sched_barrier(0);

    f32x4 sf[4];
#pragma unroll
    for (int cf = 0; cf < 4; ++cf) sf[cf] = {0.f, 0.f, 0.f, 0.f};
    __builtin_amdgcn_s_setprio(1);
#pragma unroll
    for (int ks = 0; ks < 2; ++ks) {
#pragma unroll
      for (int cf = 0; cf < 4; ++cf) {
        bf16x8 bq = *reinterpret_cast<const bf16x8*>(&q_lds[buf][(cf * 16 + l15) * 72 + ks * 32 + lh * 8]);
        sf[cf] = __builtin_amdgcn_mfma_f32_16x16x32_bf16(kf[ks], bq, sf[cf], 0, 0, 0);
      }
    }
    __builtin_amdgcn_s_setprio(0);

    const bool diag = (j == jt);
    const int s0 = j * 64;
    float pv[4][4];
#pragma unroll
    for (int r = 0; r < 4; ++r) {
      const int tg = t0 + w * 16 + lh * 4 + r;
      float pm = -1e30f;
#pragma unroll
      for (int cf = 0; cf < 4; ++cf) {
        float v = sf[cf][r];
        if (diag && (s0 + cf * 16 + l15) > tg) v = -1e30f;
        pv[cf][r] = v;
        pm = fmaxf(pm, v);
      }
      pm = fmaxf(pm, __shfl_xor(pm, 1));
      pm = fmaxf(pm, __shfl_xor(pm, 2));
      pm = fmaxf(pm, __shfl_xor(pm, 4));
      pm = fmaxf(pm, __shfl_xor(pm, 8));
      float mn = fmaxf(mrun[r], pm);
      float scl = exp2f(mrun[r] - mn);
      mrun[r] = mn;
      float rs = 0.f;
#pragma unroll
      for (int cf = 0; cf < 4; ++cf) {
        float e = exp2f(pv[cf][r] - mn);
        pv[cf][r] = e;
        rs += e;
      }
      rs += __shfl_xor(rs, 1);
      rs += __shfl_xor(rs, 2);
      rs += __shfl_xor(rs, 4);
      rs += __shfl_xor(rs, 8);
      lrun[r] = lrun[r] * scl + rs;
#pragma unroll
      for (int df = 0; df < 4; ++df) o[df][r] *= scl;
    }
#pragma unroll
    for (int cf = 0; cf < 4; ++cf)
#pragma unroll
      for (int r = 0; r < 4; ++r)
        p_lds[(w * 16 + lh * 4 + r) * 72 + cf * 16 + l15] = f2bf(pv[cf][r]);

    __builtin_amdgcn_s_setprio(1);
#pragma unroll
    for (int ks = 0; ks < 2; ++ks) {
      bf16x8 pa = *reinterpret_cast<const bf16x8*>(&p_lds[(w * 16 + l15) * 72 + ks * 32 + lh * 8]);
#pragma unroll
      for (int df = 0; df < 4; ++df) {
        bf16x8 bv = *reinterpret_cast<const bf16x8*>(&v_lds[buf][(df * 16 + l15) * 72 + ks * 32 + lh * 8]);
        o[df] = __builtin_amdgcn_mfma_f32_16x16x32_bf16(pa, bv, o[df], 0, 0, 0);
      }
    }
    __builtin_amdgcn_s_setprio(0);
  }

#pragma unroll
  for (int r = 0; r < 4; ++r) {
    float inv = 1.f / lrun[r];
    int row = t0 + w * 16 + lh * 4 + r;
#pragma unroll
    for (int df = 0; df < 4; ++df)
      out[base + (size_t)row * HD_ + df * 16 + l15] = o[df][r] * inv;
  }
}

extern "C" void kernel_launch(void* const* d_in, const int* in_sizes, int n_in,
                              void* d_out, int out_size, void* d_ws, size_t ws_size,
                              hipStream_t stream) {
  const float* x  = (const float*)d_in[0];
  const float* Wk = (const float*)d_in[1];
  const float* Wq = (const float*)d_in[2];
  const float* Wv = (const float*)d_in[3];
  float* out = (float*)d_out;

  char* ws = (char*)d_ws;
  unsigned short* wf = (unsigned short*)ws;                                  // 384 KB
  unsigned short* kb = (unsigned short*)(ws + 524288);                       // 4 MB
  unsigned short* qb = (unsigned short*)(ws + 524288 + 4 * 1024 * 1024);     // 4 MB
  unsigned short* vb = (unsigned short*)(ws + 524288 + 8 * 1024 * 1024);     // 4 MB

  hipLaunchKernelGGL(wconv_kernel, dim3(768), dim3(256), 0, stream, Wk, Wq, Wv, wf);
  hipLaunchKernelGGL(qkv_kernel, dim3(1024), dim3(256), 0, stream, x, wf, kb, qb, vb);
  hipLaunchKernelGGL(attn_kernel, dim3(512), dim3(256), 0, stream, kb, qb, vb, out);
}

// Round 9
// 97.956 us; speedup vs baseline: 1.1990x; 1.1990x over previous
//
#include <hip/hip_runtime.h>
#include <hip/hip_bf16.h>

#define B_ 16
#define T_ 2048
#define C_ 1024
#define HD_ 64

typedef __attribute__((ext_vector_type(8))) short bf16x8;
typedef __attribute__((ext_vector_type(4))) float f32x4;

__device__ __forceinline__ unsigned short f2bf(float f) {
  return __builtin_bit_cast(unsigned short, __float2bfloat16(f));
}

__device__ __forceinline__ bf16x8 cvt8(float4 a, float4 b) {
  bf16x8 r;
  r[0] = (short)f2bf(a.x); r[1] = (short)f2bf(a.y);
  r[2] = (short)f2bf(a.z); r[3] = (short)f2bf(a.w);
  r[4] = (short)f2bf(b.x); r[5] = (short)f2bf(b.y);
  r[6] = (short)f2bf(b.z); r[7] = (short)f2bf(b.w);
  return r;
}

// ---- W convert: per-K-step tiles w3[kk][n] (kk=0..15, 24KB tiles) ----
// LDS elem n: row = n>>6 (192 rows = output col, 128B lines), chunk c=(n>>3)&7, e=n&7.
// Logical k = kk*64 + ((c ^ (row&7))*8 + e); m = row>>6, d = row&63.
// Scale 1/sqrt(C)*log2(e) folded into Wk -> scores in exp2 domain.
__global__ void wconv_kernel(const float* __restrict__ Wk, const float* __restrict__ Wq,
                             const float* __restrict__ Wv, unsigned short* __restrict__ w3) {
  int o = blockIdx.x * 256 + threadIdx.x;   // 16*12288 = 196608 total
  if (o >= 16 * 12288) return;
  int kk = o / 12288;
  int n = o - kk * 12288;
  int row = n >> 6;
  int c = (n >> 3) & 7;
  int e = n & 7;
  int k = kk * 64 + (((c ^ (row & 7)) << 3) | e);
  int m = row >> 6, d = row & 63;
  const float* W = (m == 0) ? Wk : (m == 1) ? Wq : Wv;
  float v = W[k * HD_ + d];
  if (m == 0) v *= 0.03125f * 1.44269504088896f;
  w3[o] = f2bf(v);
}

// ---------------- QKV projection v7b: 1 block/CU, minimal W traffic ----------------
// 256 blocks x 512 threads (8 waves). Block: 128 rows x 192 cols; W read once per CU.
// BK=64: 24KB W tile dbuf LDS via global_load_lds (pre-swizzled), constant-queue
// counted vmcnt(7) (3 stage + 4 x per half-step), 2 barriers/step, rolled x2 loop.
// Depth-1 x prefetch: each half-step's loads are consumed by the NEXT half-step.
__global__ __launch_bounds__(512, 2) void qkv_kernel(const float* __restrict__ x,
                                                     const unsigned short* __restrict__ w3,
                                                     unsigned short* __restrict__ kb,
                                                     unsigned short* __restrict__ qb,
                                                     unsigned short* __restrict__ vb) {
  __shared__ __align__(16) unsigned short wl[2 * 12288];   // 2 x 24576 B

  const int tid = threadIdx.x;
  const int lane = tid & 63;
  const int w = tid >> 6;            // 8 waves
  const int l15 = lane & 15, lh = lane >> 4;
  const int r0 = blockIdx.x * 128;

  const float* xp = x + (size_t)(r0 + w * 16 + l15) * C_ + lh * 8;
  // frag read offsets: row l15 within 16-row group (128B stride), chunk^(l15&7) swizzle
  const int fb0 = l15 * 64 + ((lh ^ (l15 & 7)) << 3);
  const int fb1 = l15 * 64 + (((4 | lh) ^ (l15 & 7)) << 3);

  f32x4 acc[12];
#pragma unroll
  for (int i = 0; i < 12; ++i) acc[i] = {0.f, 0.f, 0.f, 0.f};

  float4 xa0, xa1, xa2, xa3, xb0, xb1, xb2, xb3;

#define STAGE(BUF, KK)                                                              \
  do {                                                                              \
    _Pragma("unroll")                                                               \
    for (int i_ = 0; i_ < 3; ++i_) {                                                \
      const int eo_ = ((w * 3 + i_) << 9) + lane * 8;   /* ushort offset in tile */ \
      __builtin_amdgcn_global_load_lds(                                             \
          (const __attribute__((address_space(1))) void*)(w3 + (KK) * 12288 + eo_), \
          (__attribute__((address_space(3))) void*)&wl[(BUF) * 12288 + eo_],        \
          16, 0, 0);                                                                \
    }                                                                               \
  } while (0)

#define XLOADA(KK) do { const float* p_ = xp + (KK) * 64;                      \
    xa0 = *(const float4*)(p_);      xa1 = *(const float4*)(p_ + 4);           \
    xa2 = *(const float4*)(p_ + 32); xa3 = *(const float4*)(p_ + 36); } while (0)
#define XLOADB(KK) do { const float* p_ = xp + (KK) * 64;                      \
    xb0 = *(const float4*)(p_);      xb1 = *(const float4*)(p_ + 4);           \
    xb2 = *(const float4*)(p_ + 32); xb3 = *(const float4*)(p_ + 36); } while (0)

#define COMPUTE(BUF, X0, X1, X2, X3)                                                \
  do {                                                                              \
    bf16x8 a0 = cvt8(X0, X1);                                                       \
    bf16x8 a1 = cvt8(X2, X3);                                                       \
    _Pragma("unroll")                                                               \
    for (int f_ = 0; f_ < 12; ++f_) {                                               \
      bf16x8 b0 = *(const bf16x8*)&wl[(BUF) * 12288 + f_ * 1024 + fb0];             \
      acc[f_] = __builtin_amdgcn_mfma_f32_16x16x32_bf16(a0, b0, acc[f_], 0, 0, 0);  \
      bf16x8 b1 = *(const bf16x8*)&wl[(BUF) * 12288 + f_ * 1024 + fb1];             \
      acc[f_] = __builtin_amdgcn_mfma_f32_16x16x32_bf16(a1, b1, acc[f_], 0, 0, 0);  \
    }                                                                               \
  } while (0)

#define SB __builtin_amdgcn_sched_barrier(0)
#define WAIT(VM)                                                  \
  do {                                                            \
    SB;                                                           \
    asm volatile("s_waitcnt vmcnt(" #VM ")" ::: "memory");        \
    SB;                                                           \
    __builtin_amdgcn_s_barrier();                                 \
  } while (0)

  // prologue: stage(0)->buf0 + x(0)  (7 outstanding)
  STAGE(0, 0);
  SB;
  XLOADA(0);
  SB;

#pragma unroll 1
  for (int it = 0; it < 7; ++it) {
    const int k2 = it * 2;
    // body A (kk=k2): issue next half-step {stage(k2+1)->buf1, x(k2+1)->xb}
    STAGE(1, k2 + 1);
    SB;
    XLOADB(k2 + 1);
    WAIT(7);                       // drains stage(k2)+x(k2); leaves 7 in flight
    COMPUTE(0, xa0, xa1, xa2, xa3);
    __builtin_amdgcn_s_barrier();
    // body B (kk=k2+1): issue {stage(k2+2)->buf0, x(k2+2)->xa}
    STAGE(0, k2 + 2);
    SB;
    XLOADA(k2 + 2);
    WAIT(7);                       // drains stage(k2+1)+x(k2+1)
    COMPUTE(1, xb0, xb1, xb2, xb3);
    __builtin_amdgcn_s_barrier();
  }
  // peeled kk=14: issue {stage(15)->buf1, x(15)->xb}
  STAGE(1, 15);
  SB;
  XLOADB(15);
  WAIT(7);                         // drains stage(14)+x(14)
  COMPUTE(0, xa0, xa1, xa2, xa3);
  __builtin_amdgcn_s_barrier();
  // peeled kk=15
  WAIT(0);
  COMPUTE(1, xb0, xb1, xb2, xb3);

#undef WAIT
#undef SB
#undef COMPUTE
#undef XLOADB
#undef XLOADA
#undef STAGE

  // epilogue: C/D layout col=lane&15, row=(lane>>4)*4+rr (scales pre-folded)
#pragma unroll
  for (int cf = 0; cf < 4; ++cf) {
    int col = cf * 16 + l15;
#pragma unroll
    for (int r = 0; r < 4; ++r) {
      size_t row = (size_t)(r0 + w * 16 + lh * 4 + r);
      kb[row * HD_ + col] = f2bf(acc[cf][r]);
      qb[row * HD_ + col] = f2bf(acc[4 + cf][r]);
      vb[row * HD_ + col] = f2bf(acc[8 + cf][r]);
    }
  }
}

// ---------------- flash attention v2 (unchanged from round 4) ----------------
__global__ __launch_bounds__(256) void attn_kernel(const unsigned short* __restrict__ kb,
                                                   const unsigned short* __restrict__ qb,
                                                   const unsigned short* __restrict__ vb,
                                                   float* __restrict__ out) {
  __shared__ __align__(16) unsigned short q_lds[2][64 * 72];
  __shared__ __align__(16) unsigned short v_lds[2][64 * 72];
  __shared__ __align__(16) unsigned short p_lds[64 * 72];

  const int tid = threadIdx.x;
  const int lane = tid & 63;
  const int w = tid >> 6;
  const int bid = blockIdx.x;
  const int idx = bid >> 4;
  const int jt = (idx < 16) ? (31 - idx) : (idx - 16);
  const int b = bid & 15;
  const int t0 = jt * 64;
  const int l15 = lane & 15;
  const int lh = lane >> 4;
  const size_t base = (size_t)b * T_ * HD_;

  const int qrow = tid >> 3, qc8 = tid & 7;
  const int vss = tid & 63, vd0 = (tid >> 6) * 8;

  bf16x8 kf[2];
#pragma unroll
  for (int ks = 0; ks < 2; ++ks)
    kf[ks] = *reinterpret_cast<const bf16x8*>(
        &kb[base + (size_t)(t0 + w * 16 + l15) * HD_ + ks * 32 + lh * 8]);

  bf16x8 qr0, qr1, vr0, vr1;
  qr0 = *reinterpret_cast<const bf16x8*>(&qb[base + (size_t)qrow * HD_ + qc8 * 8]);
  qr1 = *reinterpret_cast<const bf16x8*>(&qb[base + (size_t)(qrow + 32) * HD_ + qc8 * 8]);
  vr0 = *reinterpret_cast<const bf16x8*>(&vb[base + (size_t)vss * HD_ + vd0]);
  vr1 = *reinterpret_cast<const bf16x8*>(&vb[base + (size_t)vss * HD_ + vd0 + 32]);

  f32x4 o[4];
#pragma unroll
  for (int i = 0; i < 4; ++i) o[i] = {0.f, 0.f, 0.f, 0.f};
  float mrun[4], lrun[4];
#pragma unroll
  for (int r = 0; r < 4; ++r) { mrun[r] = -1e30f; lrun[r] = 0.f; }

  for (int j = 0; j <= jt; ++j) {
    const int buf = j & 1;
    *reinterpret_cast<bf16x8*>(&q_lds[buf][qrow * 72 + qc8 * 8]) = qr0;
    *reinterpret_cast<bf16x8*>(&q_lds[buf][(qrow + 32) * 72 + qc8 * 8]) = qr1;
#pragma unroll
    for (int jj = 0; jj < 8; ++jj) v_lds[buf][(vd0 + jj) * 72 + vss] = (unsigned short)vr0[jj];
#pragma unroll
    for (int jj = 0; jj < 8; ++jj) v_lds[buf][(vd0 + 32 + jj) * 72 + vss] = (unsigned short)vr1[jj];
    __syncthreads();

    if (j < jt) {
      const size_t sb = base + (size_t)(j + 1) * 64 * HD_;
      qr0 = *reinterpret_cast<const bf16x8*>(&qb[sb + (size_t)qrow * HD_ + qc8 * 8]);
      qr1 = *reinterpret_cast<const bf16x8*>(&qb[sb + (size_t)(qrow + 32) * HD_ + qc8 * 8]);
      vr0 = *reinterpret_cast<const bf16x8*>(&vb[sb + (size_t)vss * HD_ + vd0]);
      vr1 = *reinterpret_cast<const bf16x8*>(&vb[sb + (size_t)vss * HD_ + vd0 + 32]);
    }
    __builtin_amdgcn_sched_barrier(0);

    f32x4 sf[4];
#pragma unroll
    for (int cf = 0; cf < 4; ++cf) sf[cf] = {0.f, 0.f, 0.f, 0.f};
    __builtin_amdgcn_s_setprio(1);
#pragma unroll
    for (int ks = 0; ks < 2; ++ks) {
#pragma unroll
      for (int cf = 0; cf < 4; ++cf) {
        bf16x8 bq = *reinterpret_cast<const bf16x8*>(&q_lds[buf][(cf * 16 + l15) * 72 + ks * 32 + lh * 8]);
        sf[cf] = __builtin_amdgcn_mfma_f32_16x16x32_bf16(kf[ks], bq, sf[cf], 0, 0, 0);
      }
    }
    __builtin_amdgcn_s_setprio(0);

    const bool diag = (j == jt);
    const int s0 = j * 64;
    float pv[4][4];
#pragma unroll
    for (int r = 0; r < 4; ++r) {
      const int tg = t0 + w * 16 + lh * 4 + r;
      float pm = -1e30f;
#pragma unroll
      for (int cf = 0; cf < 4; ++cf) {
        float v = sf[cf][r];
        if (diag && (s0 + cf * 16 + l15) > tg) v = -1e30f;
        pv[cf][r] = v;
        pm = fmaxf(pm, v);
      }
      pm = fmaxf(pm, __shfl_xor(pm, 1));
      pm = fmaxf(pm, __shfl_xor(pm, 2));
      pm = fmaxf(pm, __shfl_xor(pm, 4));
      pm = fmaxf(pm, __shfl_xor(pm, 8));
      float mn = fmaxf(mrun[r], pm);
      float scl = exp2f(mrun[r] - mn);
      mrun[r] = mn;
      float rs = 0.f;
#pragma unroll
      for (int cf = 0; cf < 4; ++cf) {
        float e = exp2f(pv[cf][r] - mn);
        pv[cf][r] = e;
        rs += e;
      }
      rs += __shfl_xor(rs, 1);
      rs += __shfl_xor(rs, 2);
      rs += __shfl_xor(rs, 4);
      rs += __shfl_xor(rs, 8);
      lrun[r] = lrun[r] * scl + rs;
#pragma unroll
      for (int df = 0; df < 4; ++df) o[df][r] *= scl;
    }
#pragma unroll
    for (int cf = 0; cf < 4; ++cf)
#pragma unroll
      for (int r = 0; r < 4; ++r)
        p_lds[(w * 16 + lh * 4 + r) * 72 + cf * 16 + l15] = f2bf(pv[cf][r]);

    __builtin_amdgcn_s_setprio(1);
#pragma unroll
    for (int ks = 0; ks < 2; ++ks) {
      bf16x8 pa = *reinterpret_cast<const bf16x8*>(&p_lds[(w * 16 + l15) * 72 + ks * 32 + lh * 8]);
#pragma unroll
      for (int df = 0; df < 4; ++df) {
        bf16x8 bv = *reinterpret_cast<const bf16x8*>(&v_lds[buf][(df * 16 + l15) * 72 + ks * 32 + lh * 8]);
        o[df] = __builtin_amdgcn_mfma_f32_16x16x32_bf16(pa, bv, o[df], 0, 0, 0);
      }
    }
    __builtin_amdgcn_s_setprio(0);
  }

#pragma unroll
  for (int r = 0; r < 4; ++r) {
    float inv = 1.f / lrun[r];
    int row = t0 + w * 16 + lh * 4 + r;
#pragma unroll
    for (int df = 0; df < 4; ++df)
      out[base + (size_t)row * HD_ + df * 16 + l15] = o[df][r] * inv;
  }
}

extern "C" void kernel_launch(void* const* d_in, const int* in_sizes, int n_in,
                              void* d_out, int out_size, void* d_ws, size_t ws_size,
                              hipStream_t stream) {
  const float* x  = (const float*)d_in[0];
  const float* Wk = (const float*)d_in[1];
  const float* Wq = (const float*)d_in[2];
  const float* Wv = (const float*)d_in[3];
  float* out = (float*)d_out;

  char* ws = (char*)d_ws;
  unsigned short* w3 = (unsigned short*)ws;                                  // 384 KB
  unsigned short* kb = (unsigned short*)(ws + 524288);                       // 4 MB
  unsigned short* qb = (unsigned short*)(ws + 524288 + 4 * 1024 * 1024);     // 4 MB
  unsigned short* vb = (unsigned short*)(ws + 524288 + 8 * 1024 * 1024);     // 4 MB

  hipLaunchKernelGGL(wconv_kernel, dim3(768), dim3(256), 0, stream, Wk, Wq, Wv, w3);
  hipLaunchKernelGGL(qkv_kernel, dim3(256), dim3(512), 0, stream, x, w3, kb, qb, vb);
  hipLaunchKernelGGL(attn_kernel, dim3(512), dim3(256), 0, stream, kb, qb, vb, out);
}

// Round 10
// 92.197 us; speedup vs baseline: 1.2739x; 1.0625x over previous
//
#include <hip/hip_runtime.h>
#include <hip/hip_bf16.h>

#define B_ 16
#define T_ 2048
#define C_ 1024
#define HD_ 64

typedef __attribute__((ext_vector_type(8))) short bf16x8;
typedef __attribute__((ext_vector_type(4))) float f32x4;

__device__ __forceinline__ unsigned short f2bf(float f) {
  return __builtin_bit_cast(unsigned short, __float2bfloat16(f));
}

// ---- W convert: 8 phase-tiles of 48KB, fragment-row layout with XOR chunk swizzle ----
// w8 ushort index o = p*24576 + n.  n: row = n>>7 (0..191 = output col), phys chunk
// pc = (n>>3)&15 (16B chunks), e = n&7.  Logical chunk c = pc ^ (row&7);
// k = p*128 + c*8 + e; m = row>>6, d = row&63; value = W_m[k][d] (*scale for m==0).
__global__ void wconv_kernel(const float* __restrict__ Wk, const float* __restrict__ Wq,
                             const float* __restrict__ Wv, unsigned short* __restrict__ w8) {
  int o = blockIdx.x * 256 + threadIdx.x;   // 8*24576 = 196608 total
  if (o >= 196608) return;
  int p = o / 24576;
  int n = o - p * 24576;
  int row = n >> 7;
  int pc = (n >> 3) & 15;
  int e = n & 7;
  int c = pc ^ (row & 7);
  int k = p * 128 + c * 8 + e;
  int m = row >> 6, d = row & 63;
  const float* W = (m == 0) ? Wk : (m == 1) ? Wq : Wv;
  float v = W[k * HD_ + d];
  if (m == 0) v *= 0.03125f * 1.44269504088896f;   // 1/sqrt(C) * log2(e)
  w8[o] = f2bf(v);
}

// ---------------- QKV projection v8: 8-phase resident-W, coalesced x ----------------
// 256 blocks x 512 threads (8 waves), 128 rows/block, all 192 cols.
// LDS 128KB: W dbuf 2x48KB (per-phase 128-K tile, global_load_lds from pre-swizzled
// w8) + 8x4KB wave-private x tiles (staged from CONTIGUOUS 512B global reads, cvt to
// bf16 on the way). Per phase per wave: 48 MFMA + 52 swizzled ds_read between
// barriers; 8 barriers total; counted vmcnt only.
__global__ __launch_bounds__(512, 1) void qkv_kernel(const float* __restrict__ x,
                                                     const unsigned short* __restrict__ w8,
                                                     unsigned short* __restrict__ kb,
                                                     unsigned short* __restrict__ qb,
                                                     unsigned short* __restrict__ vb) {
  __shared__ __align__(16) unsigned short lds[65536];   // 131072 B

  const int tid = threadIdx.x;
  const int lane = tid & 63;
  const int w = tid >> 6;              // 8 waves
  const int l15 = lane & 15, lh = lane >> 4;
  const int r0 = blockIdx.x * 128;
  const int xbase = 49152 + w * 2048;  // wave-private x tile (ushort idx)
  const int ro = lane >> 5, q = lane & 31;

  f32x4 acc[12];
#pragma unroll
  for (int i = 0; i < 12; ++i) acc[i] = {0.f, 0.f, 0.f, 0.f};

  float4 xr[8];

#define STAGEW(BUF, P)                                                                \
  do {                                                                                \
    _Pragma("unroll")                                                                 \
    for (int i_ = 0; i_ < 6; ++i_) {                                                  \
      const int eo_ = i_ * 4096 + tid * 8;                                            \
      __builtin_amdgcn_global_load_lds(                                               \
          (const __attribute__((address_space(1))) void*)(w8 + (P) * 24576 + eo_),    \
          (__attribute__((address_space(3))) void*)&lds[(BUF) * 24576 + eo_],         \
          16, 0, 0);                                                                  \
    }                                                                                 \
  } while (0)

  // contiguous x read: lanes 0-31 = 512B of row j*2+0, lanes 32-63 = row j*2+1
#define XLOAD(P)                                                                      \
  do {                                                                                \
    const float* bp_ = x + (size_t)(r0 + w * 16 + ro) * C_ + (P) * 128 + q * 4;       \
    _Pragma("unroll")                                                                 \
    for (int j_ = 0; j_ < 8; ++j_)                                                    \
      xr[j_] = *(const float4*)(bp_ + (size_t)(j_ * 2) * C_);                         \
  } while (0)

#define XWRITE()                                                                      \
  do {                                                                                \
    _Pragma("unroll")                                                                 \
    for (int j_ = 0; j_ < 8; ++j_) {                                                  \
      const int row_ = j_ * 2 + ro;                                                   \
      const int idx_ = xbase + row_ * 128 + (((q >> 1) ^ (row_ & 7)) << 3) + (q & 1) * 4; \
      ushort4 hv_;                                                                    \
      hv_.x = f2bf(xr[j_].x); hv_.y = f2bf(xr[j_].y);                                 \
      hv_.z = f2bf(xr[j_].z); hv_.w = f2bf(xr[j_].w);                                 \
      *(ushort4*)&lds[idx_] = hv_;                                                    \
    }                                                                                 \
  } while (0)

#define COMPUTE(WB)                                                                   \
  do {                                                                                \
    _Pragma("unroll")                                                                 \
    for (int kk_ = 0; kk_ < 4; ++kk_) {                                               \
      const int sc_ = ((kk_ * 4 + lh) ^ (l15 & 7)) << 3;                              \
      bf16x8 a_ = *(const bf16x8*)&lds[xbase + l15 * 128 + sc_];                      \
      _Pragma("unroll")                                                               \
      for (int cf_ = 0; cf_ < 12; ++cf_) {                                            \
        bf16x8 b_ = *(const bf16x8*)&lds[(WB) + (cf_ * 16 + l15) * 128 + sc_];        \
        acc[cf_] = __builtin_amdgcn_mfma_f32_16x16x32_bf16(a_, b_, acc[cf_], 0, 0, 0);\
      }                                                                               \
    }                                                                                 \
  } while (0)

#define SB __builtin_amdgcn_sched_barrier(0)

  // prologue: W(0)+x(0) in flight; write x(0); one full drain before phase 0
  STAGEW(0, 0);
  SB;
  XLOAD(0);
  SB;
  asm volatile("s_waitcnt vmcnt(0)" ::: "memory");
  SB;
  XWRITE();
  __builtin_amdgcn_s_barrier();

#pragma unroll 1
  for (int p = 0; p < 8; ++p) {
    const int wb = (p & 1) * 24576;
    if (p < 7) {
      XLOAD(p + 1);            // 8 contiguous loads (oldest in queue)
      SB;
      STAGEW((p + 1) & 1, p + 1);  // 6 gload_lds
      SB;
    }
    COMPUTE(wb);               // 48 MFMA + 52 ds_read, covers the loads
    if (p < 7) {
      SB;
      asm volatile("s_waitcnt vmcnt(6)" ::: "memory");   // x(p+1) regs arrived
      SB;
      XWRITE();                // wave-private; overwrites x(p) after its reads
      SB;
      asm volatile("s_waitcnt vmcnt(0)" ::: "memory");   // W(p+1) landed in LDS
      SB;
      __builtin_amdgcn_s_barrier();
    }
  }

#undef SB
#undef COMPUTE
#undef XWRITE
#undef XLOAD
#undef STAGEW

  // epilogue: C/D layout col=lane&15, row=(lane>>4)*4+rr (scales pre-folded in wconv)
#pragma unroll
  for (int cf = 0; cf < 4; ++cf) {
    int col = cf * 16 + l15;
#pragma unroll
    for (int r = 0; r < 4; ++r) {
      size_t row = (size_t)(r0 + w * 16 + lh * 4 + r);
      kb[row * HD_ + col] = f2bf(acc[cf][r]);
      qb[row * HD_ + col] = f2bf(acc[4 + cf][r]);
      vb[row * HD_ + col] = f2bf(acc[8 + cf][r]);
    }
  }
}

// ---------------- flash attention v2 (unchanged from round 4) ----------------
__global__ __launch_bounds__(256) void attn_kernel(const unsigned short* __restrict__ kb,
                                                   const unsigned short* __restrict__ qb,
                                                   const unsigned short* __restrict__ vb,
                                                   float* __restrict__ out) {
  __shared__ __align__(16) unsigned short q_lds[2][64 * 72];
  __shared__ __align__(16) unsigned short v_lds[2][64 * 72];
  __shared__ __align__(16) unsigned short p_lds[64 * 72];

  const int tid = threadIdx.x;
  const int lane = tid & 63;
  const int w = tid >> 6;
  const int bid = blockIdx.x;
  const int idx = bid >> 4;
  const int jt = (idx < 16) ? (31 - idx) : (idx - 16);
  const int b = bid & 15;
  const int t0 = jt * 64;
  const int l15 = lane & 15;
  const int lh = lane >> 4;
  const size_t base = (size_t)b * T_ * HD_;

  const int qrow = tid >> 3, qc8 = tid & 7;
  const int vss = tid & 63, vd0 = (tid >> 6) * 8;

  bf16x8 kf[2];
#pragma unroll
  for (int ks = 0; ks < 2; ++ks)
    kf[ks] = *reinterpret_cast<const bf16x8*>(
        &kb[base + (size_t)(t0 + w * 16 + l15) * HD_ + ks * 32 + lh * 8]);

  bf16x8 qr0, qr1, vr0, vr1;
  qr0 = *reinterpret_cast<const bf16x8*>(&qb[base + (size_t)qrow * HD_ + qc8 * 8]);
  qr1 = *reinterpret_cast<const bf16x8*>(&qb[base + (size_t)(qrow + 32) * HD_ + qc8 * 8]);
  vr0 = *reinterpret_cast<const bf16x8*>(&vb[base + (size_t)vss * HD_ + vd0]);
  vr1 = *reinterpret_cast<const bf16x8*>(&vb[base + (size_t)vss * HD_ + vd0 + 32]);

  f32x4 o[4];
#pragma unroll
  for (int i = 0; i < 4; ++i) o[i] = {0.f, 0.f, 0.f, 0.f};
  float mrun[4], lrun[4];
#pragma unroll
  for (int r = 0; r < 4; ++r) { mrun[r] = -1e30f; lrun[r] = 0.f; }

  for (int j = 0; j <= jt; ++j) {
    const int buf = j & 1;
    *reinterpret_cast<bf16x8*>(&q_lds[buf][qrow * 72 + qc8 * 8]) = qr0;
    *reinterpret_cast<bf16x8*>(&q_lds[buf][(qrow + 32) * 72 + qc8 * 8]) = qr1;
#pragma unroll
    for (int jj = 0; jj < 8; ++jj) v_lds[buf][(vd0 + jj) * 72 + vss] = (unsigned short)vr0[jj];
#pragma unroll
    for (int jj = 0; jj < 8; ++jj) v_lds[buf][(vd0 + 32 + jj) * 72 + vss] = (unsigned short)vr1[jj];
    __syncthreads();

    if (j < jt) {
      const size_t sb = base + (size_t)(j + 1) * 64 * HD_;
      qr0 = *reinterpret_cast<const bf16x8*>(&qb[sb + (size_t)qrow * HD_ + qc8 * 8]);
      qr1 = *reinterpret_cast<const bf16x8*>(&qb[sb + (size_t)(qrow + 32) * HD_ + qc8 * 8]);
      vr0 = *reinterpret_cast<const bf16x8*>(&vb[sb + (size_t)vss * HD_ + vd0]);
      vr1 = *reinterpret_cast<const bf16x8*>(&vb[sb + (size_t)vss * HD_ + vd0 + 32]);
    }
    __builtin_amdgcn_sched_barrier(0);

    f32x4 sf[4];
#pragma unroll
    for (int cf = 0; cf < 4; ++cf) sf[cf] = {0.f, 0.f, 0.f, 0.f};
    __builtin_amdgcn_s_setprio(1);
#pragma unroll
    for (int ks = 0; ks < 2; ++ks) {
#pragma unroll
      for (int cf = 0; cf < 4; ++cf) {
        bf16x8 bq = *reinterpret_cast<const bf16x8*>(&q_lds[buf][(cf * 16 + l15) * 72 + ks * 32 + lh * 8]);
        sf[cf] = __builtin_amdgcn_mfma_f32_16x16x32_bf16(kf[ks], bq, sf[cf], 0, 0, 0);
      }
    }
    __builtin_amdgcn_s_setprio(0);

    const bool diag = (j == jt);
    const int s0 = j * 64;
    float pv[4][4];
#pragma unroll
    for (int r = 0; r < 4; ++r) {
      const int tg = t0 + w * 16 + lh * 4 + r;
      float pm = -1e30f;
#pragma unroll
      for (int cf = 0; cf < 4; ++cf) {
        float v = sf[cf][r];
        if (diag && (s0 + cf * 16 + l15) > tg) v = -1e30f;
        pv[cf][r] = v;
        pm = fmaxf(pm, v);
      }
      pm = fmaxf(pm, __shfl_xor(pm, 1));
      pm = fmaxf(pm, __shfl_xor(pm, 2));
      pm = fmaxf(pm, __shfl_xor(pm, 4));
      pm = fmaxf(pm, __shfl_xor(pm, 8));
      float mn = fmaxf(mrun[r], pm);
      float scl = exp2f(mrun[r] - mn);
      mrun[r] = mn;
      float rs = 0.f;
#pragma unroll
      for (int cf = 0; cf < 4; ++cf) {
        float e = exp2f(pv[cf][r] - mn);
        pv[cf][r] = e;
        rs += e;
      }
      rs += __shfl_xor(rs, 1);
      rs += __shfl_xor(rs, 2);
      rs += __shfl_xor(rs, 4);
      rs += __shfl_xor(rs, 8);
      lrun[r] = lrun[r] * scl + rs;
#pragma unroll
      for (int df = 0; df < 4; ++df) o[df][r] *= scl;
    }
#pragma unroll
    for (int cf = 0; cf < 4; ++cf)
#pragma unroll
      for (int r = 0; r < 4; ++r)
        p_lds[(w * 16 + lh * 4 + r) * 72 + cf * 16 + l15] = f2bf(pv[cf][r]);

    __builtin_amdgcn_s_setprio(1);
#pragma unroll
    for (int ks = 0; ks < 2; ++ks) {
      bf16x8 pa = *reinterpret_cast<const bf16x8*>(&p_lds[(w * 16 + l15) * 72 + ks * 32 + lh * 8]);
#pragma unroll
      for (int df = 0; df < 4; ++df) {
        bf16x8 bv = *reinterpret_cast<const bf16x8*>(&v_lds[buf][(df * 16 + l15) * 72 + ks * 32 + lh * 8]);
        o[df] = __builtin_amdgcn_mfma_f32_16x16x32_bf16(pa, bv, o[df], 0, 0, 0);
      }
    }
    __builtin_amdgcn_s_setprio(0);
  }

#pragma unroll
  for (int r = 0; r < 4; ++r) {
    float inv = 1.f / lrun[r];
    int row = t0 + w * 16 + lh * 4 + r;
#pragma unroll
    for (int df = 0; df < 4; ++df)
      out[base + (size_t)row * HD_ + df * 16 + l15] = o[df][r] * inv;
  }
}

extern "C" void kernel_launch(void* const* d_in, const int* in_sizes, int n_in,
                              void* d_out, int out_size, void* d_ws, size_t ws_size,
                              hipStream_t stream) {
  const float* x  = (const float*)d_in[0];
  const float* Wk = (const float*)d_in[1];
  const float* Wq = (const float*)d_in[2];
  const float* Wv = (const float*)d_in[3];
  float* out = (float*)d_out;

  char* ws = (char*)d_ws;
  unsigned short* w8 = (unsigned short*)ws;                                  // 384 KB
  unsigned short* kb = (unsigned short*)(ws + 524288);                       // 4 MB
  unsigned short* qb = (unsigned short*)(ws + 524288 + 4 * 1024 * 1024);     // 4 MB
  unsigned short* vb = (unsigned short*)(ws + 524288 + 8 * 1024 * 1024);     // 4 MB

  hipLaunchKernelGGL(wconv_kernel, dim3(768), dim3(256), 0, stream, Wk, Wq, Wv, w8);
  hipLaunchKernelGGL(qkv_kernel, dim3(256), dim3(512), 0, stream, x, w8, kb, qb, vb);
  hipLaunchKernelGGL(attn_kernel, dim3(512), dim3(256), 0, stream, kb, qb, vb, out);
}